// Round 10
// baseline (200.838 us; speedup 1.0000x reference)
//
#include <hip/hip_runtime.h>
#include <hip/hip_bf16.h>
#include <cstddef>

#define Bb 32
#define Tt 1000
#define Ii 256
#define Hh 512
#define CHK 192      // 3 gemm waves x 64 t per chunk
#define NCHK 6       // 5*192 + 40 tail

typedef __attribute__((ext_vector_type(8))) short short8;
typedef __attribute__((ext_vector_type(4))) float f32x4;

__device__ __forceinline__ unsigned short f2bfu(float f) {
  return __builtin_bit_cast(unsigned short, __float2bfloat16(f));
}

// ---- scan NP pairs (2 timesteps per LDS u32), serial LIF recurrence ----
template <int NP>
__device__ __forceinline__ void scan_run(const unsigned int* cw,
                                         float* zp, float* tp,
                                         float& v, bool& zb, float& tr) {
  const float dm = 0.9512294245007140f, om = 0.0487705754992860f;
  unsigned int ring[8];
#pragma unroll
  for (int j = 0; j < 8; ++j)
    if (j < NP) ring[j] = cw[j];

  auto step = [&](unsigned int bits16, int t) {
    const float cur = __builtin_bit_cast(float, bits16 << 16);  // bf16 -> f32
    const float omc = om * cur;
    const float w = fmaf(v, dm, omc);     // speculative no-reset path
    v = zb ? omc : w;                     // multiplicative reset on old z
    zb = v > 1.0f;                        // spike((v-THR)/THR), THR=1
    tr = fmaf(tr, dm, zb ? om : 0.0f);    // exp_convolve
    __builtin_nontemporal_store(zb ? 1.0f : 0.0f, zp + (size_t)t * Hh);
    __builtin_nontemporal_store(tr, tp + (size_t)t * Hh);
  };

  int g = 0;
  for (; g + 8 <= NP; g += 8) {
#pragma unroll
    for (int j = 0; j < 8; ++j) {
      const unsigned int c2 = ring[j];
      if (g + j + 8 < NP) ring[j] = cw[g + j + 8];
      step(c2 & 0xffffu, 2 * (g + j));
      step(c2 >> 16, 2 * (g + j) + 1);
    }
  }
#pragma unroll
  for (int j = 0; j < 8; ++j) {
    if (j < (NP & 7)) {
      const unsigned int c2 = ring[j];
      step(c2 & 0xffffu, 2 * (g + j));
      step(c2 >> 16, 2 * (g + j) + 1);
    }
  }
}

// Fused GEMM + LIF scan. Block = (b, 64-h tile): 256 blocks = 1/CU, 4 waves.
// wave0 scans chunk k (192 t) while waves1-3 MFMA chunk k+1 (64 t each).
__global__ __launch_bounds__(256, 1) void lif_fused(const float* __restrict__ X,
                                                    const float* __restrict__ W,
                                                    float* __restrict__ Z,
                                                    float* __restrict__ TR) {
  __shared__ short Ws[64 * 256];        // W tile bf16, 16B-slot XOR swizzle
  __shared__ short cc[2][64 * 194];     // currents [h][192+2pad] bf16, dbuf

  const int tid = threadIdx.x;
  const int ht = blockIdx.x;            // 0..7
  const int b = blockIdx.y;             // 0..31
  const int lane = tid & 63;
  const int wid = tid >> 6;             // 0..3
  const int fl = lane & 15, fj = lane >> 4;

  // ---- stage W tile once: rows ht*64..+63 -> bf16 LDS ----
  {
    const int h = tid >> 2;
    const int j = tid & 3;
    const float* wg = W + (size_t)(ht * 64 + h) * Ii;
#pragma unroll
    for (int q = 0; q < 8; ++q) {
      const int slot = j * 8 + q;       // 0..31 (8 bf16 = 16B per slot)
      f32x4 w0 = *(const f32x4*)(wg + slot * 8);
      f32x4 w1 = *(const f32x4*)(wg + slot * 8 + 4);
      short8 wv;
#pragma unroll
      for (int e = 0; e < 4; ++e) {
        wv[e] = (short)f2bfu(w0[e]);
        wv[4 + e] = (short)f2bfu(w1[e]);
      }
      *(short8*)(Ws + h * 256 + ((slot ^ (h & 7)) << 3)) = wv;
    }
  }
  __syncthreads();

  // ---- GEMM one 64t x 64h x 256k stripe into cc buffer (waves 1..3) ----
  auto gemm_chunk = [&](int c, short* ccb) {
    const int ts = (wid - 1) * 64;
    const int t0 = c * CHK + ts;
    f32x4 acc[4][4];
#pragma unroll
    for (int i = 0; i < 4; ++i)
#pragma unroll
      for (int j = 0; j < 4; ++j) acc[i][j] = (f32x4)0.0f;

    const float* xb[4];
#pragma unroll
    for (int mi = 0; mi < 4; ++mi) {
      int row = t0 + mi * 16 + fl;
      row = (row < Tt) ? row : (Tt - 1);  // clamp tail (results unread)
      xb[mi] = X + ((size_t)b * Tt + row) * Ii + (fj << 3);
    }

#define LOADA(dst, s)                                                   \
  {                                                                     \
    _Pragma("unroll") for (int mi = 0; mi < 4; ++mi) {                  \
      dst[mi][0] = *(const f32x4*)(xb[mi] + (s) * 32);                  \
      dst[mi][1] = *(const f32x4*)(xb[mi] + (s) * 32 + 4);              \
    }                                                                   \
  }
#define KSTEP(src, s)                                                   \
  {                                                                     \
    short8 af[4];                                                       \
    _Pragma("unroll") for (int mi = 0; mi < 4; ++mi) {                  \
      _Pragma("unroll") for (int e = 0; e < 4; ++e) {                   \
        af[mi][e] = (short)f2bfu(src[mi][0][e]);                        \
        af[mi][4 + e] = (short)f2bfu(src[mi][1][e]);                    \
      }                                                                 \
    }                                                                   \
    _Pragma("unroll") for (int nj = 0; nj < 4; ++nj) {                  \
      const int h0 = nj * 16 + fl;                                      \
      const int slot = (s) * 4 + fj;                                    \
      short8 bfr = *(const short8*)(Ws + h0 * 256 +                     \
                                    ((slot ^ (h0 & 7)) << 3));          \
      _Pragma("unroll") for (int mi = 0; mi < 4; ++mi)                  \
        acc[mi][nj] = __builtin_amdgcn_mfma_f32_16x16x32_bf16(          \
            af[mi], bfr, acc[mi][nj], 0, 0, 0);                         \
    }                                                                   \
  }

    f32x4 a0[4][2], a1[4][2];
    LOADA(a0, 0);
    LOADA(a1, 1);
#pragma unroll
    for (int sp = 0; sp < 4; ++sp) {
      KSTEP(a0, 2 * sp);
      if (sp < 3) LOADA(a0, 2 * sp + 2);
      KSTEP(a1, 2 * sp + 1);
      if (sp < 3) LOADA(a1, 2 * sp + 3);
    }
#undef LOADA
#undef KSTEP

    // acc -> cc[h][t] bf16, rows packed in pairs (C/D: col=lane&15, row=fj*4+q)
#pragma unroll
    for (int nj = 0; nj < 4; ++nj) {
      const int h = nj * 16 + fl;
#pragma unroll
      for (int mi = 0; mi < 4; ++mi) {
        const int r = ts + mi * 16 + fj * 4;
#pragma unroll
        for (int qp = 0; qp < 2; ++qp) {
          const unsigned int pk =
              ((unsigned int)f2bfu(acc[mi][nj][2 * qp + 1]) << 16) |
              f2bfu(acc[mi][nj][2 * qp]);
          *(unsigned int*)(ccb + h * 194 + r + 2 * qp) = pk;
        }
      }
    }
  };

  // ---- pipeline: scan chunk c (wave0) || GEMM chunk c+1 (waves1-3) ----
  float v = 0.0f, tr = 0.0f;
  bool zb = false;

  if (wid != 0) gemm_chunk(0, cc[0]);
  __syncthreads();

  for (int c = 0; c < NCHK; ++c) {
    if (wid == 0) {
      const unsigned int* cw = (const unsigned int*)(cc[c & 1] + lane * 194);
      float* zp = Z + ((size_t)b * Tt + c * CHK) * Hh + ht * 64 + lane;
      float* tp = TR + ((size_t)b * Tt + c * CHK) * Hh + ht * 64 + lane;
      if (c < NCHK - 1)
        scan_run<96>(cw, zp, tp, v, zb, tr);
      else
        scan_run<20>(cw, zp, tp, v, zb, tr);   // tail: 40 steps
    } else if (c + 1 < NCHK) {
      gemm_chunk(c + 1, cc[(c + 1) & 1]);
    }
    __syncthreads();
  }
}

extern "C" void kernel_launch(void* const* d_in, const int* in_sizes, int n_in,
                              void* d_out, int out_size, void* d_ws, size_t ws_size,
                              hipStream_t stream) {
  const float* x = (const float*)d_in[0];   // [B,T,I] f32
  const float* W = (const float*)d_in[1];   // [H,I]  f32
  float* out = (float*)d_out;
  float* zout = out;                                  // [B,T,H]
  float* trout = out + (size_t)Bb * Tt * Hh;          // [B,T,H]

  dim3 grid(8, 32), block(256);
  hipLaunchKernelGGL(lif_fused, grid, block, 0, stream, x, W, zout, trout);
}

// Round 12
// 185.180 us; speedup vs baseline: 1.0846x; 1.0846x over previous
//
#include <hip/hip_runtime.h>
#include <hip/hip_bf16.h>
#include <cstddef>

#define Bb 32
#define Tt 1000
#define Ii 256
#define Hh 512

typedef __attribute__((ext_vector_type(8))) short short8;
typedef __attribute__((ext_vector_type(4))) float f32x4;

__device__ __forceinline__ unsigned short f2bfu(float f) {
  return __builtin_bit_cast(unsigned short, __float2bfloat16(f));
}

// ---- scan NP pairs (2 timesteps per LDS u32), serial LIF recurrence ----
template <int NP>
__device__ __forceinline__ void scan_run(const unsigned int* cw,
                                         float* zp, float* tp,
                                         float& v, bool& zb, float& tr) {
  const float dm = 0.9512294245007140f, om = 0.0487705754992860f;
  unsigned int ring[8];
#pragma unroll
  for (int j = 0; j < 8; ++j)
    if (j < NP) ring[j] = cw[j];

  auto step = [&](unsigned int bits16, int t) {
    const float cur = __builtin_bit_cast(float, bits16 << 16);  // bf16 -> f32
    const float omc = om * cur;
    const float w = fmaf(v, dm, omc);     // speculative no-reset path
    v = zb ? omc : w;                     // multiplicative reset on old z
    zb = v > 1.0f;                        // spike((v-THR)/THR), THR=1
    tr = fmaf(tr, dm, zb ? om : 0.0f);    // exp_convolve
    __builtin_nontemporal_store(zb ? 1.0f : 0.0f, zp + (size_t)t * Hh);
    __builtin_nontemporal_store(tr, tp + (size_t)t * Hh);
  };

  int g = 0;
  for (; g + 8 <= NP; g += 8) {
#pragma unroll
    for (int j = 0; j < 8; ++j) {
      const unsigned int c2 = ring[j];
      if (g + j + 8 < NP) ring[j] = cw[g + j + 8];
      step(c2 & 0xffffu, 2 * (g + j));
      step(c2 >> 16, 2 * (g + j) + 1);
    }
  }
#pragma unroll
  for (int j = 0; j < 8; ++j) {
    if (j < (NP & 7)) {
      const unsigned int c2 = ring[j];
      step(c2 & 0xffffu, 2 * (g + j));
      step(c2 >> 16, 2 * (g + j) + 1);
    }
  }
}

// =================== x f32 -> bf16 preconvert (once) ===================
__global__ __launch_bounds__(256) void cvt_x(const float* __restrict__ X,
                                             short* __restrict__ XBF) {
  const int gt = blockIdx.x * 256 + threadIdx.x;  // 32000 rows * 64
  const int row = gt >> 6, j = gt & 63;
  f32x4 xv = *(const f32x4*)(X + (size_t)row * Ii + j * 4);
  uint2 o;
  o.x = ((unsigned)f2bfu(xv[1]) << 16) | f2bfu(xv[0]);
  o.y = ((unsigned)f2bfu(xv[3]) << 16) | f2bfu(xv[2]);
  *(uint2*)(XBF + (size_t)row * Ii + j * 4) = o;
}

// =================== fused v2: deep-pipelined producer/consumer ===================
// 256 blocks (8 ht x 32 b) = 1/CU, 4 waves: wave0 scans chunk c while waves1-3
// (each a private 32-t stripe) MFMA chunk c+1 and async-stage chunk c+2.
#define CHK2 96
#define NCHK2 11      // 10*96 + tail 40

__global__ __launch_bounds__(256, 1) void lif_fused2(const short* __restrict__ XBF,
                                                     const float* __restrict__ Wf,
                                                     float* __restrict__ Z,
                                                     float* __restrict__ TR) {
  __shared__ short Ab[2][CHK2 * 256];   // A chunk bf16, dbuf (2 x 48 KB)
  __shared__ short cc[2][64 * 98];      // currents [h][96+2 pad] bf16, dbuf

  const int tid = threadIdx.x;
  const int ht = blockIdx.x;            // 0..7
  const int b = blockIdx.y;             // 0..31
  const int lane = tid & 63;
  const int wid = tid >> 6;             // 0: scan, 1..3: gemm
  const int fl = lane & 15, fj = lane >> 4;
  const int ts = (wid - 1) * 32;        // gemm stripe t-offset

  // ---- hoist W fragments to registers (32 frags = 128 VGPR, LDS-bound so free) ----
  short8 wfrag[8][4];
  if (wid) {
#pragma unroll
    for (int s = 0; s < 8; ++s)
#pragma unroll
      for (int nj = 0; nj < 4; ++nj) {
        const float* wp = Wf + (size_t)(ht * 64 + nj * 16 + fl) * Ii + s * 32 + fj * 8;
        f32x4 w0 = *(const f32x4*)wp, w1 = *(const f32x4*)(wp + 4);
        short8 vv;
#pragma unroll
        for (int e = 0; e < 4; ++e) {
          vv[e] = (short)f2bfu(w0[e]);
          vv[4 + e] = (short)f2bfu(w1[e]);
        }
        wfrag[s][nj] = vv;
      }
  }

  const short* xb = XBF + (size_t)b * Tt * Ii;

  // stage own 32-t stripe of A[c] into Ab[buf] via global_load_lds (16B/lane).
  // LDS is linear [t][slot16B]; source k pre-swizzled: slot s' holds ks = s'^(t&7).
  auto stage = [&](int c, int buf) {
#pragma unroll
    for (int i = 0; i < 16; ++i) {
      const int tloc = ts + 2 * i + (lane >> 5);
      const int sp = lane & 31;
      const int ks = sp ^ (tloc & 7);
      int tg = c * CHK2 + tloc;
      tg = tg < Tt ? tg : (Tt - 1);       // tail clamp (rows unread)
      const short* src = xb + (size_t)tg * Ii + ks * 8;
      __builtin_amdgcn_global_load_lds(
          (const __attribute__((address_space(1))) void*)src,
          (__attribute__((address_space(3))) void*)(&Ab[buf][(ts + 2 * i) * 256]),
          16, 0, 0);
    }
  };

  // compute own 32t x 64h x 256k stripe from Ab[buf] -> cc buffer
  auto gemm_chunk = [&](int buf, short* ccb) {
    f32x4 acc[2][4];
#pragma unroll
    for (int mt = 0; mt < 2; ++mt)
#pragma unroll
      for (int nj = 0; nj < 4; ++nj) acc[mt][nj] = (f32x4)0.0f;

    const short* Abase = &Ab[buf][0];
#pragma unroll
    for (int s = 0; s < 8; ++s) {
      short8 af[2];
#pragma unroll
      for (int mt = 0; mt < 2; ++mt) {
        const int tloc = ts + mt * 16 + fl;
        const int slot = (4 * s + fj) ^ (tloc & 7);
        af[mt] = *(const short8*)(Abase + tloc * 256 + slot * 8);
      }
#pragma unroll
      for (int mt = 0; mt < 2; ++mt)
#pragma unroll
        for (int nj = 0; nj < 4; ++nj)
          acc[mt][nj] = __builtin_amdgcn_mfma_f32_16x16x32_bf16(
              af[mt], wfrag[s][nj], acc[mt][nj], 0, 0, 0);
    }
    // C/D: col=lane&15 -> h = nj*16+fl; row = fj*4+q -> t = ts+mt*16+fj*4+q
#pragma unroll
    for (int mt = 0; mt < 2; ++mt)
#pragma unroll
      for (int nj = 0; nj < 4; ++nj) {
        const int h = nj * 16 + fl;
        const int r = ts + mt * 16 + fj * 4;
#pragma unroll
        for (int qp = 0; qp < 2; ++qp) {
          const unsigned int pk =
              ((unsigned)f2bfu(acc[mt][nj][2 * qp + 1]) << 16) |
              f2bfu(acc[mt][nj][2 * qp]);
          *(unsigned int*)(ccb + h * 98 + r + 2 * qp) = pk;
        }
      }
  };

  // ---- prologue: stage A0,A1; compute chunk0 -> cc[0] ----
  if (wid) {
    stage(0, 0);
    stage(1, 1);
    asm volatile("s_waitcnt vmcnt(16)" ::: "memory");   // A0 landed
    gemm_chunk(0, &cc[0][0]);
    asm volatile("s_waitcnt lgkmcnt(0)" ::: "memory");  // cc[0] visible
  }
  __builtin_amdgcn_s_barrier();
  asm volatile("" ::: "memory");

  float v = 0.0f, tr = 0.0f;
  bool zb = false;

  for (int c = 0; c < NCHK2; ++c) {
    if (wid == 0) {
      const unsigned int* cw = (const unsigned int*)(&cc[c & 1][0] + lane * 98);
      float* zp = Z + ((size_t)b * Tt + c * CHK2) * Hh + ht * 64 + lane;
      float* tp = TR + ((size_t)b * Tt + c * CHK2) * Hh + ht * 64 + lane;
      if (c < NCHK2 - 1)
        scan_run<48>(cw, zp, tp, v, zb, tr);
      else
        scan_run<20>(cw, zp, tp, v, zb, tr);   // tail: 40 t
    } else {
      if (c + 2 < NCHK2) {
        stage(c + 2, c & 1);                          // async, spans this chunk
        asm volatile("s_waitcnt vmcnt(16)" ::: "memory");  // A[c+1] landed
      } else if (c + 1 < NCHK2) {
        asm volatile("s_waitcnt vmcnt(0)" ::: "memory");
      }
      if (c + 1 < NCHK2) {
        gemm_chunk((c + 1) & 1, &cc[(c + 1) & 1][0]);
        asm volatile("s_waitcnt lgkmcnt(0)" ::: "memory");
      }
    }
    __builtin_amdgcn_s_barrier();
    asm volatile("" ::: "memory");
  }
}

// =================== fallback (ws too small): round-10 kernel, HW-verified ===================
#define CHK 192
#define NCHK 6

__global__ __launch_bounds__(256, 1) void lif_fused(const float* __restrict__ X,
                                                    const float* __restrict__ W,
                                                    float* __restrict__ Z,
                                                    float* __restrict__ TR) {
  __shared__ short Ws[64 * 256];
  __shared__ short cc[2][64 * 194];

  const int tid = threadIdx.x;
  const int ht = blockIdx.x;
  const int b = blockIdx.y;
  const int lane = tid & 63;
  const int wid = tid >> 6;
  const int fl = lane & 15, fj = lane >> 4;

  {
    const int h = tid >> 2;
    const int j = tid & 3;
    const float* wg = W + (size_t)(ht * 64 + h) * Ii;
#pragma unroll
    for (int q = 0; q < 8; ++q) {
      const int slot = j * 8 + q;
      f32x4 w0 = *(const f32x4*)(wg + slot * 8);
      f32x4 w1 = *(const f32x4*)(wg + slot * 8 + 4);
      short8 wv;
#pragma unroll
      for (int e = 0; e < 4; ++e) {
        wv[e] = (short)f2bfu(w0[e]);
        wv[4 + e] = (short)f2bfu(w1[e]);
      }
      *(short8*)(Ws + h * 256 + ((slot ^ (h & 7)) << 3)) = wv;
    }
  }
  __syncthreads();

  auto gemm_chunk = [&](int c, short* ccb) {
    const int ts = (wid - 1) * 64;
    const int t0 = c * CHK + ts;
    f32x4 acc[4][4];
#pragma unroll
    for (int i = 0; i < 4; ++i)
#pragma unroll
      for (int j = 0; j < 4; ++j) acc[i][j] = (f32x4)0.0f;

    const float* xbp[4];
#pragma unroll
    for (int mi = 0; mi < 4; ++mi) {
      int row = t0 + mi * 16 + fl;
      row = (row < Tt) ? row : (Tt - 1);
      xbp[mi] = X + ((size_t)b * Tt + row) * Ii + (fj << 3);
    }

#define LOADA(dst, s)                                                   \
  {                                                                     \
    _Pragma("unroll") for (int mi = 0; mi < 4; ++mi) {                  \
      dst[mi][0] = *(const f32x4*)(xbp[mi] + (s) * 32);                 \
      dst[mi][1] = *(const f32x4*)(xbp[mi] + (s) * 32 + 4);             \
    }                                                                   \
  }
#define KSTEP(src, s)                                                   \
  {                                                                     \
    short8 af[4];                                                       \
    _Pragma("unroll") for (int mi = 0; mi < 4; ++mi) {                  \
      _Pragma("unroll") for (int e = 0; e < 4; ++e) {                   \
        af[mi][e] = (short)f2bfu(src[mi][0][e]);                        \
        af[mi][4 + e] = (short)f2bfu(src[mi][1][e]);                    \
      }                                                                 \
    }                                                                   \
    _Pragma("unroll") for (int nj = 0; nj < 4; ++nj) {                  \
      const int h0 = nj * 16 + fl;                                      \
      const int slot = (s) * 4 + fj;                                    \
      short8 bfr = *(const short8*)(Ws + h0 * 256 +                     \
                                    ((slot ^ (h0 & 7)) << 3));          \
      _Pragma("unroll") for (int mi = 0; mi < 4; ++mi)                  \
        acc[mi][nj] = __builtin_amdgcn_mfma_f32_16x16x32_bf16(          \
            af[mi], bfr, acc[mi][nj], 0, 0, 0);                         \
    }                                                                   \
  }

    f32x4 a0[4][2], a1[4][2];
    LOADA(a0, 0);
    LOADA(a1, 1);
#pragma unroll
    for (int sp = 0; sp < 4; ++sp) {
      KSTEP(a0, 2 * sp);
      if (sp < 3) LOADA(a0, 2 * sp + 2);
      KSTEP(a1, 2 * sp + 1);
      if (sp < 3) LOADA(a1, 2 * sp + 3);
    }
#undef LOADA
#undef KSTEP

#pragma unroll
    for (int nj = 0; nj < 4; ++nj) {
      const int h = nj * 16 + fl;
#pragma unroll
      for (int mi = 0; mi < 4; ++mi) {
        const int r = ts + mi * 16 + fj * 4;
#pragma unroll
        for (int qp = 0; qp < 2; ++qp) {
          const unsigned int pk =
              ((unsigned int)f2bfu(acc[mi][nj][2 * qp + 1]) << 16) |
              f2bfu(acc[mi][nj][2 * qp]);
          *(unsigned int*)(ccb + h * 194 + r + 2 * qp) = pk;
        }
      }
    }
  };

  float v = 0.0f, tr = 0.0f;
  bool zb = false;

  if (wid != 0) gemm_chunk(0, cc[0]);
  __syncthreads();

  for (int c = 0; c < NCHK; ++c) {
    if (wid == 0) {
      const unsigned int* cw = (const unsigned int*)(cc[c & 1] + lane * 194);
      float* zp = Z + ((size_t)b * Tt + c * CHK) * Hh + ht * 64 + lane;
      float* tp = TR + ((size_t)b * Tt + c * CHK) * Hh + ht * 64 + lane;
      if (c < NCHK - 1)
        scan_run<96>(cw, zp, tp, v, zb, tr);
      else
        scan_run<20>(cw, zp, tp, v, zb, tr);
    } else if (c + 1 < NCHK) {
      gemm_chunk(c + 1, cc[(c + 1) & 1]);
    }
    __syncthreads();
  }
}

extern "C" void kernel_launch(void* const* d_in, const int* in_sizes, int n_in,
                              void* d_out, int out_size, void* d_ws, size_t ws_size,
                              hipStream_t stream) {
  const float* x = (const float*)d_in[0];   // [B,T,I] f32
  const float* W = (const float*)d_in[1];   // [H,I]  f32
  float* out = (float*)d_out;
  float* zout = out;                                  // [B,T,H]
  float* trout = out + (size_t)Bb * Tt * Hh;          // [B,T,H]

  const size_t xbf_bytes = (size_t)Bb * Tt * Ii * sizeof(short);  // 16.4 MB
  if (ws_size >= xbf_bytes) {
    short* xbf = (short*)d_ws;
    hipLaunchKernelGGL(cvt_x, dim3(8000), dim3(256), 0, stream, x, xbf);
    hipLaunchKernelGGL(lif_fused2, dim3(8, 32), dim3(256), 0, stream,
                       xbf, W, zout, trout);
  } else {
    hipLaunchKernelGGL(lif_fused, dim3(8, 32), dim3(256), 0, stream,
                       x, W, zout, trout);
  }
}